// Round 26
// baseline (223.752 us; speedup 1.0000x reference)
//
#include <hip/hip_runtime.h>
#include <hip/hip_bf16.h>

// B=4, T=4096, E=512, H=64. out fp32 [B,T,H].
#define Bn 4
#define Tn 4096
#define En 512
#define Hn 64
#define NEGINF -3e38f
// 0.125 (1/sqrt(64)) * log2(e): QK^T output lands in log2 domain
#define QSCALE 0.1803368801f

typedef __attribute__((ext_vector_type(8))) __bf16 bf16x8;
typedef __attribute__((ext_vector_type(4))) __bf16 bf16x4;
typedef __attribute__((ext_vector_type(4))) float f32x4;

#define MFMA16(a, b, c) __builtin_amdgcn_mfma_f32_16x16x32_bf16(a, b, c, 0, 0, 0)

__device__ __forceinline__ float bf2f(unsigned short u) {
    union { unsigned u; float f; } v; v.u = ((unsigned)u) << 16;
    return v.f;
}
__device__ __forceinline__ unsigned cvtpk(float a, float b) {
    unsigned d;
    asm("v_cvt_pk_bf16_f32 %0, %1, %2" : "=v"(d) : "v"(a), "v"(b));
    return d;
}
__device__ __forceinline__ unsigned short f2bf(float f) {
    union { float f; unsigned u; } v; v.f = f;
    unsigned r = v.u + 0x7fffu + ((v.u >> 16) & 1u);
    return (unsigned short)(r >> 16);
}
__device__ __forceinline__ float exp2fast(float x) {
    float r;
    asm("v_exp_f32 %0, %1" : "=v"(r) : "v"(x));
    return r;
}
// async global->LDS DMA, 16B per lane; lds dest is wave-uniform base + lane*16
__device__ __forceinline__ void gl16(const void* g, void* l) {
    __builtin_amdgcn_global_load_lds(
        (const __attribute__((address_space(1))) unsigned int*)g,
        (__attribute__((address_space(3))) unsigned int*)l, 16, 0, 0);
}

// ---------------- kernel 1: fused QKV projection (64-row tiles) --------------
// 256 blocks x 512 thr (8 waves: rsel=(w&3)*16 of 64 rows, csel=(w>>2)*96).
// A 8KB + W 24KB double-buffered (64KB), T14 reg-staged prefetch, ONE
// barrier/step. q16 pre-scaled by QSCALE so attn's QK^T lands in log2 domain.
__launch_bounds__(512, 2)
__global__ void proj(const float* __restrict__ x, const float* __restrict__ Wq,
                     const float* __restrict__ Wk, const float* __restrict__ Wv,
                     unsigned short* __restrict__ q16, unsigned short* __restrict__ k16,
                     unsigned short* __restrict__ vt16) {
    __shared__ __align__(16) unsigned char plds[2][32768];  // [buf][A 8KB | W 24KB]
    const int tid = threadIdx.x;
    const int w = tid >> 6, lane = tid & 63, r = lane & 15, g = lane >> 4;
    const int row0 = blockIdx.x * 64;
    const int rsel = (w & 3) * 16, csel = (w >> 2) * 96;

    const int srow = tid >> 3, skc = (tid & 7) * 8;   // A staging: row (0..63), k-off
    const int sby = (tid & 7) * 16;                   // byte col in LDS row
    f32x4 acc[6];
#pragma unroll
    for (int i = 0; i < 6; ++i) acc[i] = (f32x4){0.f, 0.f, 0.f, 0.f};

    // prologue: stage k-step 0 into buf 0
    {
        const float4* xp = (const float4*)&x[(row0 + srow) * En + skc];
        float4 f0 = xp[0], f1 = xp[1];
        union { bf16x8 v; unsigned u32[4]; } t;
        t.u32[0] = cvtpk(f0.x, f0.y); t.u32[1] = cvtpk(f0.z, f0.w);
        t.u32[2] = cvtpk(f1.x, f1.y); t.u32[3] = cvtpk(f1.z, f1.w);
        *(bf16x8*)&plds[0][srow * 128 + (sby ^ ((srow & 7) << 4))] = t.v;
#pragma unroll
        for (int i = 0; i < 3; ++i) {
            int chunk = tid + i * 512;
            int wrow = chunk >> 3, kc = (chunk & 7) * 8, by = (chunk & 7) * 16;
            const float* Ws = (wrow < 64) ? &Wq[wrow * En]
                             : (wrow < 128) ? &Wk[(wrow - 64) * En] : &Wv[(wrow - 128) * En];
            const float4* wp = (const float4*)&Ws[kc];
            float4 w0 = wp[0], w1 = wp[1];
            union { bf16x8 v; unsigned u32[4]; } tw;
            tw.u32[0] = cvtpk(w0.x, w0.y); tw.u32[1] = cvtpk(w0.z, w0.w);
            tw.u32[2] = cvtpk(w1.x, w1.y); tw.u32[3] = cvtpk(w1.z, w1.w);
            *(bf16x8*)&plds[0][8192 + wrow * 128 + (by ^ ((wrow & 7) << 4))] = tw.v;
        }
    }
    __syncthreads();

    for (int s = 0; s < 8; ++s) {
        const int pp = s & 1;
        const bool more = (s < 7);
        // T14: prefetch next k-step into regs (raw fp32 until write phase)
        float4 nf0, nf1;
        float4 nw0[3], nw1[3];
        if (more) {
            int k1 = (s + 1) * 64;
            const float4* xp = (const float4*)&x[(row0 + srow) * En + k1 + skc];
            nf0 = xp[0]; nf1 = xp[1];
#pragma unroll
            for (int i = 0; i < 3; ++i) {
                int chunk = tid + i * 512;
                int wrow = chunk >> 3, kc = (chunk & 7) * 8;
                const float* Ws = (wrow < 64) ? &Wq[wrow * En]
                                 : (wrow < 128) ? &Wk[(wrow - 64) * En] : &Wv[(wrow - 128) * En];
                const float4* wp = (const float4*)&Ws[k1 + kc];
                nw0[i] = wp[0]; nw1[i] = wp[1];
            }
        }
        // compute from buf pp
        {
            const unsigned char* A = &plds[pp][0];
            const unsigned char* W = &plds[pp][8192];
            int arow = rsel + r, asw = (arow & 7) << 4;
            bf16x8 a0 = *(const bf16x8*)&A[arow * 128 + ((g * 16) ^ asw)];
            bf16x8 a1 = *(const bf16x8*)&A[arow * 128 + ((64 + g * 16) ^ asw)];
#pragma unroll
            for (int ct = 0; ct < 6; ++ct) {
                int wrow = csel + ct * 16 + r, wsw = (wrow & 7) << 4;
                bf16x8 b0 = *(const bf16x8*)&W[wrow * 128 + ((g * 16) ^ wsw)];
                bf16x8 b1 = *(const bf16x8*)&W[wrow * 128 + ((64 + g * 16) ^ wsw)];
                acc[ct] = MFMA16(a0, b0, acc[ct]);
                acc[ct] = MFMA16(a1, b1, acc[ct]);
            }
        }
        // write prefetched tile into buf pp^1, one barrier
        if (more) {
            unsigned char* D = &plds[pp ^ 1][0];
            union { bf16x8 v; unsigned u32[4]; } t;
            t.u32[0] = cvtpk(nf0.x, nf0.y); t.u32[1] = cvtpk(nf0.z, nf0.w);
            t.u32[2] = cvtpk(nf1.x, nf1.y); t.u32[3] = cvtpk(nf1.z, nf1.w);
            *(bf16x8*)&D[srow * 128 + (sby ^ ((srow & 7) << 4))] = t.v;
#pragma unroll
            for (int i = 0; i < 3; ++i) {
                int chunk = tid + i * 512;
                int wrow = chunk >> 3, by = (chunk & 7) * 16;
                union { bf16x8 v; unsigned u32[4]; } tw;
                tw.u32[0] = cvtpk(nw0[i].x, nw0[i].y); tw.u32[1] = cvtpk(nw0[i].z, nw0[i].w);
                tw.u32[2] = cvtpk(nw1[i].x, nw1[i].y); tw.u32[3] = cvtpk(nw1[i].z, nw1[i].w);
                *(bf16x8*)&D[8192 + wrow * 128 + (by ^ ((wrow & 7) << 4))] = tw.v;
            }
        }
        __syncthreads();
    }
    // epilogue: C layout col = lane&15, row = (lane>>4)*4 + reg
#pragma unroll
    for (int ct = 0; ct < 6; ++ct) {
        int n = csel + ct * 16 + r;
#pragma unroll
        for (int reg = 0; reg < 4; ++reg) {
            int gr = row0 + rsel + g * 4 + reg;
            if (n < 64) {
                q16[gr * 64 + n] = f2bf(acc[ct][reg] * QSCALE);
            } else if (n < 128) {
                k16[gr * 64 + (n - 64)] = f2bf(acc[ct][reg]);
            } else {
                int h = n - 128; int bb = gr >> 12; int t = gr & 4095;
                vt16[((bb * 64 + h) << 12) + t] = f2bf(acc[ct][reg]);
            }
        }
    }
}

// ---------------- kernel 2: attention partials + fused group merge -----------
// 1024 blocks x 256 thr (4 waves x 32 q-rows [2 qf] = 128-q tile).
// jt = (page&1)? s5 : 31-s5; piece = ((page&1)<<2)|((page>>1)<<1)|q1 (0..7).
// 4 independent blocks/CU, uniform ~16.5 tiles/CU. T4 schedule; fixed-m log2
// softmax; setprio spans QK..PV. After partial writes: device fence +
// atomicAdd(cnt[jt*4+b]); the 8th finisher merges its group's 128 rows
// (split-K completion pattern; po/lp L2-hot). cnt zeroed per launch by a
// captured hipMemsetAsync -> deterministic across graph replays.
__launch_bounds__(256, 4)
__global__ void attnp(const unsigned short* __restrict__ q16, const unsigned short* __restrict__ k16,
                      const unsigned short* __restrict__ vt16,
                      unsigned short* __restrict__ po, float* __restrict__ lp,
                      int* __restrict__ cnt, float* __restrict__ out) {
    __shared__ __align__(16) unsigned char lds[2][16384];  // [buf][K 8KB | V 8KB]
    __shared__ int lastflag;

    const int tid = threadIdx.x;
    const int w = tid >> 6, lane = tid & 63, r = lane & 15, g = lane >> 4;
    const int bid = blockIdx.x;
    const int page = bid >> 8, idx = bid & 255;
    const int s5 = idx >> 3, b = (idx >> 1) & 3, q1 = idx & 1;
    const int jt = (page & 1) ? s5 : 31 - s5;
    const int piece = ((page & 1) << 2) | ((page >> 1) << 1) | q1;   // 0..7
    const size_t kbase = (size_t)b * Tn;
    const int q0 = jt * 128;
    const int nt = 2 * (jt + 1);                    // kv64 tiles in causal span
    const int t0 = (piece * nt) >> 3;
    const int tEnd = ((piece + 1) * nt) >> 3;
    const int wq0 = q0 + w * 32;                    // wave's 32 q-rows

    const unsigned short* Kb = k16 + kbase * 64;
    const unsigned short* Vb = vt16 + ((size_t)(b * 64) << 12);

    // staging geometry: wave w owns chunks w*4..w*4+3 (1KB each: 8 rows x 128B)
    const int srl = lane >> 3, scb = (lane & 7) * 16;

    // Q B-frags: 2 qf groups of 16 q-rows (pre-scaled into log2 domain)
    bf16x8 bq[2][2];
#pragma unroll
    for (int qf = 0; qf < 2; ++qf) {
        const unsigned short* qp = &q16[(kbase + wq0 + qf * 16 + r) * 64 + g * 8];
        bq[qf][0] = *(const bf16x8*)qp;
        bq[qf][1] = *(const bf16x8*)(qp + 32);
    }

    f32x4 o[2][4];
#pragma unroll
    for (int qf = 0; qf < 2; ++qf)
#pragma unroll
        for (int i = 0; i < 4; ++i) o[qf][i] = (f32x4){0.f, 0.f, 0.f, 0.f};
    float l_[2] = {0.f, 0.f};

    // prologue: issue DMA for tile t0 into buf t0&1
    if (tEnd > t0) {
        int kv0 = t0 * 64;
        unsigned char* D = &lds[t0 & 1][0];
#pragma unroll
        for (int i = 0; i < 4; ++i) {
            int cc = w * 4 + i;
            if (cc < 8) {
                int row = cc * 8 + srl, sw = (row & 7) << 4;
                gl16((const char*)Kb + (size_t)(kv0 + row) * 128 + (scb ^ sw), D + cc * 1024);
            } else {
                int h = (cc - 8) * 8 + srl, sw = (h & 7) << 4;
                gl16((const char*)Vb + (size_t)h * 8192 + (size_t)kv0 * 2 + (scb ^ sw), D + cc * 1024);
            }
        }
    }

    for (int it = t0; it < tEnd; ++it) {
        const int pp = it & 1;
        // T4: wait only for current tile's DMA, raw barrier, then issue next
        asm volatile("s_waitcnt vmcnt(0)" ::: "memory");
        __builtin_amdgcn_s_barrier();
        __builtin_amdgcn_sched_barrier(0);
        if (it + 1 < tEnd) {
            int nkv = (it + 1) * 64;
            unsigned char* D = &lds[pp ^ 1][0];
#pragma unroll
            for (int i = 0; i < 4; ++i) {
                int cc = w * 4 + i;
                if (cc < 8) {
                    int row = cc * 8 + srl, sw = (row & 7) << 4;
                    gl16((const char*)Kb + (size_t)(nkv + row) * 128 + (scb ^ sw), D + cc * 1024);
                } else {
                    int h = (cc - 8) * 8 + srl, sw = (h & 7) << 4;
                    gl16((const char*)Vb + (size_t)h * 8192 + (size_t)nkv * 2 + (scb ^ sw), D + cc * 1024);
                }
            }
        }
        const int kv0 = it * 64;
        if (kv0 <= wq0 + 31) {                      // wave-level causal skip
            const unsigned char* K = &lds[pp][0];
            const unsigned char* V = &lds[pp][8192];
            f32x4 s4[2][4];                          // [qf][ct]
            __builtin_amdgcn_s_setprio(1);           // spans QK..PV
#pragma unroll
            for (int ct = 0; ct < 4; ++ct) {
                int row = ct * 16 + r;
                int base = row * 128, sw = (row & 7) << 4;
                bf16x8 ak0 = *(const bf16x8*)&K[base + ((g * 16) ^ sw)];
                bf16x8 ak1 = *(const bf16x8*)&K[base + ((64 + g * 16) ^ sw)];
#pragma unroll
                for (int qf = 0; qf < 2; ++qf) {
                    f32x4 t = (f32x4){0.f, 0.f, 0.f, 0.f};
                    t = MFMA16(ak0, bq[qf][0], t);
                    t = MFMA16(ak1, bq[qf][1], t);
                    s4[qf][ct] = t;
                }
            }
            // diagonal masking (log2 domain: no scale mul)
            if (kv0 + 63 > wq0) {
#pragma unroll
                for (int qf = 0; qf < 2; ++qf) {
                    int qq = wq0 + qf * 16 + r;
#pragma unroll
                    for (int ct = 0; ct < 4; ++ct)
#pragma unroll
                        for (int reg = 0; reg < 4; ++reg) {
                            int kv = kv0 + ct * 16 + g * 4 + reg;
                            if (kv > qq) s4[qf][ct][reg] = NEGINF;
                        }
                }
            }
            // fixed-m: P = exp2(S); per-lane l partial; pack (no cross-lane ops)
            union { bf16x8 v; unsigned u32[4]; } pk[2][2];
#pragma unroll
            for (int qf = 0; qf < 2; ++qf) {
#pragma unroll
                for (int ct = 0; ct < 4; ++ct)
#pragma unroll
                    for (int reg = 0; reg < 4; ++reg)
                        s4[qf][ct][reg] = exp2fast(s4[qf][ct][reg]);
                l_[qf] += ((s4[qf][0][0] + s4[qf][0][1]) + (s4[qf][0][2] + s4[qf][0][3])) +
                          ((s4[qf][1][0] + s4[qf][1][1]) + (s4[qf][1][2] + s4[qf][1][3])) +
                          ((s4[qf][2][0] + s4[qf][2][1]) + (s4[qf][2][2] + s4[qf][2][3])) +
                          ((s4[qf][3][0] + s4[qf][3][1]) + (s4[qf][3][2] + s4[qf][3][3]));
#pragma unroll
                for (int kf = 0; kf < 2; ++kf) {
                    pk[qf][kf].u32[0] = cvtpk(s4[qf][kf * 2][0], s4[qf][kf * 2][1]);
                    pk[qf][kf].u32[1] = cvtpk(s4[qf][kf * 2][2], s4[qf][kf * 2][3]);
                    pk[qf][kf].u32[2] = cvtpk(s4[qf][kf * 2 + 1][0], s4[qf][kf * 2 + 1][1]);
                    pk[qf][kf].u32[3] = cvtpk(s4[qf][kf * 2 + 1][2], s4[qf][kf * 2 + 1][3]);
                }
            }
            // PV: V frags loaded once, used by BOTH qf
#pragma unroll
            for (int cth = 0; cth < 4; ++cth) {
                int h = cth * 16 + r;
                int vb = h * 128, sw2 = (h & 7) << 4;
#pragma unroll
                for (int kf = 0; kf < 2; ++kf) {
                    int off = kf * 64 + g * 8;
                    union { bf16x8 v; bf16x4 h4[2]; } vv;
                    vv.h4[0] = *(const bf16x4*)&V[vb + (off ^ sw2)];
                    vv.h4[1] = *(const bf16x4*)&V[vb + ((off + 32) ^ sw2)];
                    o[0][cth] = MFMA16(pk[0][kf].v, vv.v, o[0][cth]);
                    o[1][cth] = MFMA16(pk[1][kf].v, vv.v, o[1][cth]);
                }
            }
            __builtin_amdgcn_s_setprio(0);
        }
    }

    // ---- write partials (always; empty piece -> zeros) ----
    const size_t qb = (size_t)piece * 16384 + b * 4096;
#pragma unroll
    for (int qf = 0; qf < 2; ++qf) {
#pragma unroll
        for (int cth = 0; cth < 4; ++cth)
#pragma unroll
            for (int reg = 0; reg < 4; ++reg)
                po[(qb + wq0 + qf * 16 + g * 4 + reg) * 64 + cth * 16 + r] = f2bf(o[qf][cth][reg]);
        // reduce l across the 4 g-lane groups (lanes r, r+16, r+32, r+48)
        float lsum = l_[qf];
        lsum += __shfl_xor(lsum, 16);
        lsum += __shfl_xor(lsum, 32);
        if (lane < 16)
            lp[qb + wq0 + qf * 16 + lane] = lsum;
    }

    // ---- split-K completion: 8th finisher merges the group's 128 rows ----
    __threadfence();                               // publish po/lp (device scope)
    if (tid == 0) {
        int old = atomicAdd(&cnt[jt * 4 + b], 1);
        lastflag = (old == 7);
    }
    __syncthreads();
    if (lastflag) {
        __threadfence();                           // order reads after observation
        const int qbase = b * 4096 + jt * 128;     // global q of group row 0
        const int c8 = (tid & 7) * 8;
#pragma unroll
        for (int rr = 0; rr < 4; ++rr) {
            int row = rr * 32 + (tid >> 3);
            size_t q = (size_t)(qbase + row);
            float L = 0.f;
#pragma unroll
            for (int c = 0; c < 8; ++c) L += lp[(size_t)c * 16384 + q];
            float inv = 1.0f / L;
            float acc[8] = {0.f, 0.f, 0.f, 0.f, 0.f, 0.f, 0.f, 0.f};
#pragma unroll
            for (int c = 0; c < 8; ++c) {
                union { uint4 v; unsigned short u[8]; } ld;
                ld.v = *(const uint4*)&po[((size_t)c * 16384 + q) * 64 + c8];
#pragma unroll
                for (int j = 0; j < 8; ++j) acc[j] += bf2f(ld.u[j]);
            }
            float4* op = (float4*)&out[q * 64 + c8];
            op[0] = (float4){acc[0] * inv, acc[1] * inv, acc[2] * inv, acc[3] * inv};
            op[1] = (float4){acc[4] * inv, acc[5] * inv, acc[6] * inv, acc[7] * inv};
        }
    }
}

extern "C" void kernel_launch(void* const* d_in, const int* in_sizes, int n_in,
                              void* d_out, int out_size, void* d_ws, size_t ws_size,
                              hipStream_t stream) {
    const float* x  = (const float*)d_in[0];
    const float* Wq = (const float*)d_in[1];
    const float* Wk = (const float*)d_in[2];
    const float* Wv = (const float*)d_in[3];
    float* out = (float*)d_out;
    char* ws = (char*)d_ws;

    unsigned short* q16 = (unsigned short*)ws;                  // 2 MiB
    unsigned short* k16 = (unsigned short*)(ws + 2097152);      // 2 MiB
    unsigned short* v16 = (unsigned short*)(ws + 4194304);      // 2 MiB
    unsigned short* po  = (unsigned short*)(ws + 6291456);      // 8*16384*64*2 = 16 MiB
    float*          lp  = (float*)(ws + 23068672);              // 8*16384*4 = 512 KiB
    int*            cnt = (int*)(ws + 23592960);                // 128 ints = 512 B
    // total ws use: ~22.5 MiB

    hipMemsetAsync(cnt, 0, 128 * sizeof(int), stream);          // captured -> per-replay
    hipLaunchKernelGGL(proj, dim3(256), dim3(512), 0, stream, x, Wq, Wk, Wv, q16, k16, v16);
    hipLaunchKernelGGL(attnp, dim3(1024), dim3(256), 0, stream, q16, k16, v16, po, lp, cnt, out);
}

// Round 27
// 40.819 us; speedup vs baseline: 5.4815x; 5.4815x over previous
//
#include <hip/hip_runtime.h>
#include <hip/hip_bf16.h>

// B=4, T=4096, E=512, H=64. out fp32 [B,T,H].
#define Bn 4
#define Tn 4096
#define En 512
#define Hn 64
#define NEGINF -3e38f
// 0.125 (1/sqrt(64)) * log2(e): QK^T output lands in log2 domain
#define QSCALE 0.1803368801f

typedef __attribute__((ext_vector_type(8))) __bf16 bf16x8;
typedef __attribute__((ext_vector_type(4))) __bf16 bf16x4;
typedef __attribute__((ext_vector_type(4))) float f32x4;

#define MFMA16(a, b, c) __builtin_amdgcn_mfma_f32_16x16x32_bf16(a, b, c, 0, 0, 0)

__device__ __forceinline__ float bf2f(unsigned short u) {
    union { unsigned u; float f; } v; v.u = ((unsigned)u) << 16;
    return v.f;
}
__device__ __forceinline__ unsigned cvtpk(float a, float b) {
    unsigned d;
    asm("v_cvt_pk_bf16_f32 %0, %1, %2" : "=v"(d) : "v"(a), "v"(b));
    return d;
}
__device__ __forceinline__ unsigned short f2bf(float f) {
    union { float f; unsigned u; } v; v.f = f;
    unsigned r = v.u + 0x7fffu + ((v.u >> 16) & 1u);
    return (unsigned short)(r >> 16);
}
__device__ __forceinline__ float exp2fast(float x) {
    float r;
    asm("v_exp_f32 %0, %1" : "=v"(r) : "v"(x));
    return r;
}
// async global->LDS DMA, 16B per lane; lds dest is wave-uniform base + lane*16
__device__ __forceinline__ void gl16(const void* g, void* l) {
    __builtin_amdgcn_global_load_lds(
        (const __attribute__((address_space(1))) unsigned int*)g,
        (__attribute__((address_space(3))) unsigned int*)l, 16, 0, 0);
}

// ---------------- kernel 1: fused QKV projection (64-row tiles) --------------
// 256 blocks x 512 thr (8 waves: rsel=(w&3)*16 of 64 rows, csel=(w>>2)*96).
// W L2 traffic halved vs 32-row tiles (256 x 384KB = 98 MB). A 8KB + W 24KB
// double-buffered (64KB), T14 reg-staged prefetch, ONE barrier/step.
// q16 pre-scaled by QSCALE so attn's QK^T lands in log2 domain.
__launch_bounds__(512, 2)
__global__ void proj(const float* __restrict__ x, const float* __restrict__ Wq,
                     const float* __restrict__ Wk, const float* __restrict__ Wv,
                     unsigned short* __restrict__ q16, unsigned short* __restrict__ k16,
                     unsigned short* __restrict__ vt16) {
    __shared__ __align__(16) unsigned char plds[2][32768];  // [buf][A 8KB | W 24KB]
    const int tid = threadIdx.x;
    const int w = tid >> 6, lane = tid & 63, r = lane & 15, g = lane >> 4;
    const int row0 = blockIdx.x * 64;
    const int rsel = (w & 3) * 16, csel = (w >> 2) * 96;

    const int srow = tid >> 3, skc = (tid & 7) * 8;   // A staging: row (0..63), k-off
    const int sby = (tid & 7) * 16;                   // byte col in LDS row
    f32x4 acc[6];
#pragma unroll
    for (int i = 0; i < 6; ++i) acc[i] = (f32x4){0.f, 0.f, 0.f, 0.f};

    // prologue: stage k-step 0 into buf 0
    {
        const float4* xp = (const float4*)&x[(row0 + srow) * En + skc];
        float4 f0 = xp[0], f1 = xp[1];
        union { bf16x8 v; unsigned u32[4]; } t;
        t.u32[0] = cvtpk(f0.x, f0.y); t.u32[1] = cvtpk(f0.z, f0.w);
        t.u32[2] = cvtpk(f1.x, f1.y); t.u32[3] = cvtpk(f1.z, f1.w);
        *(bf16x8*)&plds[0][srow * 128 + (sby ^ ((srow & 7) << 4))] = t.v;
#pragma unroll
        for (int i = 0; i < 3; ++i) {
            int chunk = tid + i * 512;
            int wrow = chunk >> 3, kc = (chunk & 7) * 8, by = (chunk & 7) * 16;
            const float* Ws = (wrow < 64) ? &Wq[wrow * En]
                             : (wrow < 128) ? &Wk[(wrow - 64) * En] : &Wv[(wrow - 128) * En];
            const float4* wp = (const float4*)&Ws[kc];
            float4 w0 = wp[0], w1 = wp[1];
            union { bf16x8 v; unsigned u32[4]; } tw;
            tw.u32[0] = cvtpk(w0.x, w0.y); tw.u32[1] = cvtpk(w0.z, w0.w);
            tw.u32[2] = cvtpk(w1.x, w1.y); tw.u32[3] = cvtpk(w1.z, w1.w);
            *(bf16x8*)&plds[0][8192 + wrow * 128 + (by ^ ((wrow & 7) << 4))] = tw.v;
        }
    }
    __syncthreads();

    for (int s = 0; s < 8; ++s) {
        const int pp = s & 1;
        const bool more = (s < 7);
        // T14: prefetch next k-step into regs (raw fp32 until write phase)
        float4 nf0, nf1;
        float4 nw0[3], nw1[3];
        if (more) {
            int k1 = (s + 1) * 64;
            const float4* xp = (const float4*)&x[(row0 + srow) * En + k1 + skc];
            nf0 = xp[0]; nf1 = xp[1];
#pragma unroll
            for (int i = 0; i < 3; ++i) {
                int chunk = tid + i * 512;
                int wrow = chunk >> 3, kc = (chunk & 7) * 8;
                const float* Ws = (wrow < 64) ? &Wq[wrow * En]
                                 : (wrow < 128) ? &Wk[(wrow - 64) * En] : &Wv[(wrow - 128) * En];
                const float4* wp = (const float4*)&Ws[k1 + kc];
                nw0[i] = wp[0]; nw1[i] = wp[1];
            }
        }
        // compute from buf pp
        {
            const unsigned char* A = &plds[pp][0];
            const unsigned char* W = &plds[pp][8192];
            int arow = rsel + r, asw = (arow & 7) << 4;
            bf16x8 a0 = *(const bf16x8*)&A[arow * 128 + ((g * 16) ^ asw)];
            bf16x8 a1 = *(const bf16x8*)&A[arow * 128 + ((64 + g * 16) ^ asw)];
#pragma unroll
            for (int ct = 0; ct < 6; ++ct) {
                int wrow = csel + ct * 16 + r, wsw = (wrow & 7) << 4;
                bf16x8 b0 = *(const bf16x8*)&W[wrow * 128 + ((g * 16) ^ wsw)];
                bf16x8 b1 = *(const bf16x8*)&W[wrow * 128 + ((64 + g * 16) ^ wsw)];
                acc[ct] = MFMA16(a0, b0, acc[ct]);
                acc[ct] = MFMA16(a1, b1, acc[ct]);
            }
        }
        // write prefetched tile into buf pp^1, one barrier
        if (more) {
            unsigned char* D = &plds[pp ^ 1][0];
            union { bf16x8 v; unsigned u32[4]; } t;
            t.u32[0] = cvtpk(nf0.x, nf0.y); t.u32[1] = cvtpk(nf0.z, nf0.w);
            t.u32[2] = cvtpk(nf1.x, nf1.y); t.u32[3] = cvtpk(nf1.z, nf1.w);
            *(bf16x8*)&D[srow * 128 + (sby ^ ((srow & 7) << 4))] = t.v;
#pragma unroll
            for (int i = 0; i < 3; ++i) {
                int chunk = tid + i * 512;
                int wrow = chunk >> 3, by = (chunk & 7) * 16;
                union { bf16x8 v; unsigned u32[4]; } tw;
                tw.u32[0] = cvtpk(nw0[i].x, nw0[i].y); tw.u32[1] = cvtpk(nw0[i].z, nw0[i].w);
                tw.u32[2] = cvtpk(nw1[i].x, nw1[i].y); tw.u32[3] = cvtpk(nw1[i].z, nw1[i].w);
                *(bf16x8*)&D[8192 + wrow * 128 + (by ^ ((wrow & 7) << 4))] = tw.v;
            }
        }
        __syncthreads();
    }
    // epilogue: C layout col = lane&15, row = (lane>>4)*4 + reg
#pragma unroll
    for (int ct = 0; ct < 6; ++ct) {
        int n = csel + ct * 16 + r;
#pragma unroll
        for (int reg = 0; reg < 4; ++reg) {
            int gr = row0 + rsel + g * 4 + reg;
            if (n < 64) {
                q16[gr * 64 + n] = f2bf(acc[ct][reg] * QSCALE);
            } else if (n < 128) {
                k16[gr * 64 + (n - 64)] = f2bf(acc[ct][reg]);
            } else {
                int h = n - 128; int bb = gr >> 12; int t = gr & 4095;
                vt16[((bb * 64 + h) << 12) + t] = f2bf(acc[ct][reg]);
            }
        }
    }
}

// ---------------- kernel 2: attention partials (128-q tiles, 8 kv-pieces) ----
// 1024 blocks x 256 thr (4 waves x 32 q-rows [2 qf] = 128-q tile).
// jt = (page&1)? s5 : 31-s5; piece = ((page&1)<<2)|((page>>1)<<1)|q1 (0..7).
// 4 independent blocks/CU, uniform ~16.5 tiles/CU. T4 schedule: {vmcnt(0);
// raw s_barrier; issue next DMA; compute}. Fixed-m log2 softmax; K/V frags
// loaded once per tile, shared across both qf. setprio(1) spans QK..PV.
// l pre-reduced across g-lanes at epilogue (2 shuffles/qf) -> lp is [piece][q].
__launch_bounds__(256, 4)
__global__ void attnp(const unsigned short* __restrict__ q16, const unsigned short* __restrict__ k16,
                      const unsigned short* __restrict__ vt16,
                      unsigned short* __restrict__ po, float* __restrict__ lp) {
    __shared__ __align__(16) unsigned char lds[2][16384];  // [buf][K 8KB | V 8KB]

    const int tid = threadIdx.x;
    const int w = tid >> 6, lane = tid & 63, r = lane & 15, g = lane >> 4;
    const int bid = blockIdx.x;
    const int page = bid >> 8, idx = bid & 255;
    const int s5 = idx >> 3, b = (idx >> 1) & 3, q1 = idx & 1;
    const int jt = (page & 1) ? s5 : 31 - s5;
    const int piece = ((page & 1) << 2) | ((page >> 1) << 1) | q1;   // 0..7
    const size_t kbase = (size_t)b * Tn;
    const int q0 = jt * 128;
    const int nt = 2 * (jt + 1);                    // kv64 tiles in causal span
    const int t0 = (piece * nt) >> 3;
    const int tEnd = ((piece + 1) * nt) >> 3;
    const int wq0 = q0 + w * 32;                    // wave's 32 q-rows

    const unsigned short* Kb = k16 + kbase * 64;
    const unsigned short* Vb = vt16 + ((size_t)(b * 64) << 12);

    // staging geometry: wave w owns chunks w*4..w*4+3 (1KB each: 8 rows x 128B)
    const int srl = lane >> 3, scb = (lane & 7) * 16;

    // Q B-frags: 2 qf groups of 16 q-rows (pre-scaled into log2 domain)
    bf16x8 bq[2][2];
#pragma unroll
    for (int qf = 0; qf < 2; ++qf) {
        const unsigned short* qp = &q16[(kbase + wq0 + qf * 16 + r) * 64 + g * 8];
        bq[qf][0] = *(const bf16x8*)qp;
        bq[qf][1] = *(const bf16x8*)(qp + 32);
    }

    f32x4 o[2][4];
#pragma unroll
    for (int qf = 0; qf < 2; ++qf)
#pragma unroll
        for (int i = 0; i < 4; ++i) o[qf][i] = (f32x4){0.f, 0.f, 0.f, 0.f};
    float l_[2] = {0.f, 0.f};

    // prologue: issue DMA for tile t0 into buf t0&1
    if (tEnd > t0) {
        int kv0 = t0 * 64;
        unsigned char* D = &lds[t0 & 1][0];
#pragma unroll
        for (int i = 0; i < 4; ++i) {
            int cc = w * 4 + i;
            if (cc < 8) {
                int row = cc * 8 + srl, sw = (row & 7) << 4;
                gl16((const char*)Kb + (size_t)(kv0 + row) * 128 + (scb ^ sw), D + cc * 1024);
            } else {
                int h = (cc - 8) * 8 + srl, sw = (h & 7) << 4;
                gl16((const char*)Vb + (size_t)h * 8192 + (size_t)kv0 * 2 + (scb ^ sw), D + cc * 1024);
            }
        }
    }

    for (int it = t0; it < tEnd; ++it) {
        const int pp = it & 1;
        // T4: wait only for current tile's DMA, raw barrier, then issue next
        asm volatile("s_waitcnt vmcnt(0)" ::: "memory");
        __builtin_amdgcn_s_barrier();
        __builtin_amdgcn_sched_barrier(0);
        if (it + 1 < tEnd) {
            int nkv = (it + 1) * 64;
            unsigned char* D = &lds[pp ^ 1][0];
#pragma unroll
            for (int i = 0; i < 4; ++i) {
                int cc = w * 4 + i;
                if (cc < 8) {
                    int row = cc * 8 + srl, sw = (row & 7) << 4;
                    gl16((const char*)Kb + (size_t)(nkv + row) * 128 + (scb ^ sw), D + cc * 1024);
                } else {
                    int h = (cc - 8) * 8 + srl, sw = (h & 7) << 4;
                    gl16((const char*)Vb + (size_t)h * 8192 + (size_t)nkv * 2 + (scb ^ sw), D + cc * 1024);
                }
            }
        }
        const int kv0 = it * 64;
        if (kv0 <= wq0 + 31) {                      // wave-level causal skip
            const unsigned char* K = &lds[pp][0];
            const unsigned char* V = &lds[pp][8192];
            f32x4 s4[2][4];                          // [qf][ct]
            __builtin_amdgcn_s_setprio(1);           // spans QK..PV
#pragma unroll
            for (int ct = 0; ct < 4; ++ct) {
                int row = ct * 16 + r;
                int base = row * 128, sw = (row & 7) << 4;
                bf16x8 ak0 = *(const bf16x8*)&K[base + ((g * 16) ^ sw)];
                bf16x8 ak1 = *(const bf16x8*)&K[base + ((64 + g * 16) ^ sw)];
#pragma unroll
                for (int qf = 0; qf < 2; ++qf) {
                    f32x4 t = (f32x4){0.f, 0.f, 0.f, 0.f};
                    t = MFMA16(ak0, bq[qf][0], t);
                    t = MFMA16(ak1, bq[qf][1], t);
                    s4[qf][ct] = t;
                }
            }
            // diagonal masking (log2 domain: no scale mul)
            if (kv0 + 63 > wq0) {
#pragma unroll
                for (int qf = 0; qf < 2; ++qf) {
                    int qq = wq0 + qf * 16 + r;
#pragma unroll
                    for (int ct = 0; ct < 4; ++ct)
#pragma unroll
                        for (int reg = 0; reg < 4; ++reg) {
                            int kv = kv0 + ct * 16 + g * 4 + reg;
                            if (kv > qq) s4[qf][ct][reg] = NEGINF;
                        }
                }
            }
            // fixed-m: P = exp2(S); per-lane l partial; pack (no cross-lane ops)
            union { bf16x8 v; unsigned u32[4]; } pk[2][2];
#pragma unroll
            for (int qf = 0; qf < 2; ++qf) {
#pragma unroll
                for (int ct = 0; ct < 4; ++ct)
#pragma unroll
                    for (int reg = 0; reg < 4; ++reg)
                        s4[qf][ct][reg] = exp2fast(s4[qf][ct][reg]);
                l_[qf] += ((s4[qf][0][0] + s4[qf][0][1]) + (s4[qf][0][2] + s4[qf][0][3])) +
                          ((s4[qf][1][0] + s4[qf][1][1]) + (s4[qf][1][2] + s4[qf][1][3])) +
                          ((s4[qf][2][0] + s4[qf][2][1]) + (s4[qf][2][2] + s4[qf][2][3])) +
                          ((s4[qf][3][0] + s4[qf][3][1]) + (s4[qf][3][2] + s4[qf][3][3]));
#pragma unroll
                for (int kf = 0; kf < 2; ++kf) {
                    pk[qf][kf].u32[0] = cvtpk(s4[qf][kf * 2][0], s4[qf][kf * 2][1]);
                    pk[qf][kf].u32[1] = cvtpk(s4[qf][kf * 2][2], s4[qf][kf * 2][3]);
                    pk[qf][kf].u32[2] = cvtpk(s4[qf][kf * 2 + 1][0], s4[qf][kf * 2 + 1][1]);
                    pk[qf][kf].u32[3] = cvtpk(s4[qf][kf * 2 + 1][2], s4[qf][kf * 2 + 1][3]);
                }
            }
            // PV: V frags loaded once, used by BOTH qf
#pragma unroll
            for (int cth = 0; cth < 4; ++cth) {
                int h = cth * 16 + r;
                int vb = h * 128, sw2 = (h & 7) << 4;
#pragma unroll
                for (int kf = 0; kf < 2; ++kf) {
                    int off = kf * 64 + g * 8;
                    union { bf16x8 v; bf16x4 h4[2]; } vv;
                    vv.h4[0] = *(const bf16x4*)&V[vb + (off ^ sw2)];
                    vv.h4[1] = *(const bf16x4*)&V[vb + ((off + 32) ^ sw2)];
                    o[0][cth] = MFMA16(pk[0][kf].v, vv.v, o[0][cth]);
                    o[1][cth] = MFMA16(pk[1][kf].v, vv.v, o[1][cth]);
                }
            }
            __builtin_amdgcn_s_setprio(0);
        }
    }

    // ---- write partials (always; empty piece -> zeros) ----
    const size_t qb = (size_t)piece * 16384 + b * 4096;
#pragma unroll
    for (int qf = 0; qf < 2; ++qf) {
#pragma unroll
        for (int cth = 0; cth < 4; ++cth)
#pragma unroll
            for (int reg = 0; reg < 4; ++reg)
                po[(qb + wq0 + qf * 16 + g * 4 + reg) * 64 + cth * 16 + r] = f2bf(o[qf][cth][reg]);
        // reduce l across the 4 g-lane groups (lanes r, r+16, r+32, r+48)
        float lsum = l_[qf];
        lsum += __shfl_xor(lsum, 16);
        lsum += __shfl_xor(lsum, 32);
        if (lane < 16)
            lp[qb + wq0 + qf * 16 + lane] = lsum;
    }
}

// ---------------- kernel 3: merge 8 kv-piece partials + normalize ------------
// 512 blocks x 256 thr; thread -> (q, 8 cols): 16B po loads; lp is [piece][q]
// (pre-reduced in attnp) -> 8 scalar loads for L instead of 32.
__global__ void merge(const unsigned short* __restrict__ po, const float* __restrict__ lp,
                      float* __restrict__ out) {
    int t = blockIdx.x * 256 + threadIdx.x;        // 0..131071
    int q = t >> 3, c8 = (t & 7) * 8;
    float L = 0.f;
#pragma unroll
    for (int c = 0; c < 8; ++c)
        L += lp[(size_t)c * 16384 + q];
    float inv = 1.0f / L;
    float acc[8] = {0.f, 0.f, 0.f, 0.f, 0.f, 0.f, 0.f, 0.f};
#pragma unroll
    for (int c = 0; c < 8; ++c) {
        union { uint4 v; unsigned short u[8]; } ld;
        ld.v = *(const uint4*)&po[((size_t)c * 16384 + q) * 64 + c8];
#pragma unroll
        for (int j = 0; j < 8; ++j) acc[j] += bf2f(ld.u[j]);
    }
    float4* op = (float4*)&out[(size_t)q * 64 + c8];
    op[0] = (float4){acc[0] * inv, acc[1] * inv, acc[2] * inv, acc[3] * inv};
    op[1] = (float4){acc[4] * inv, acc[5] * inv, acc[6] * inv, acc[7] * inv};
}

extern "C" void kernel_launch(void* const* d_in, const int* in_sizes, int n_in,
                              void* d_out, int out_size, void* d_ws, size_t ws_size,
                              hipStream_t stream) {
    const float* x  = (const float*)d_in[0];
    const float* Wq = (const float*)d_in[1];
    const float* Wk = (const float*)d_in[2];
    const float* Wv = (const float*)d_in[3];
    float* out = (float*)d_out;
    char* ws = (char*)d_ws;

    unsigned short* q16 = (unsigned short*)ws;                  // 2 MiB
    unsigned short* k16 = (unsigned short*)(ws + 2097152);      // 2 MiB
    unsigned short* v16 = (unsigned short*)(ws + 4194304);      // 2 MiB
    unsigned short* po  = (unsigned short*)(ws + 6291456);      // 8*16384*64*2 = 16 MiB
    float*          lp  = (float*)(ws + 23068672);              // 8*16384*4 = 512 KiB
    // total ws use: ~22.5 MiB

    hipLaunchKernelGGL(proj, dim3(256), dim3(512), 0, stream, x, Wq, Wk, Wv, q16, k16, v16);
    hipLaunchKernelGGL(attnp, dim3(1024), dim3(256), 0, stream, q16, k16, v16, po, lp);
    hipLaunchKernelGGL(merge, dim3(512), dim3(256), 0, stream, po, lp, out);
}